// Round 4
// baseline (1521.818 us; speedup 1.0000x reference)
//
#include <hip/hip_runtime.h>

// Lure RNN, latency-bound sequential chain.
// R7: back to the proven 8-wave lure_seq8 (R4 structure; R6's 4-wave variant
// exposed latency at 1 wave/SIMD and regressed). One surgical change: LDS
// slot stride 68 -> 70 dwords and state reads as ds_read2_b64 pairs instead
// of ds_read_b128. Old layout: bank = 4(nn+q) mod 32 -> 4 lanes/bank-quad on
// every b128 (m136 4-way, ~1.5x) = 320 conflict cyc/step (27% of LDS pipe).
// New layout: pair-bank = (35q+2nn+p) mod 16 -> exactly 2 lanes/bank = free.
// prep_w/prep_uu = R5-exact (verified, MFMA-form u-projection).

#define NT 2048

typedef __attribute__((ext_vector_type(8))) short short8;
typedef __attribute__((ext_vector_type(4))) float f4;
typedef __attribute__((ext_vector_type(2))) int i2;

union Frag { int i[4]; i2 h[2]; short8 v; };

__device__ __forceinline__ unsigned rne_bf16(float f) {
  unsigned u = __float_as_uint(f);
  return (u + 0x7FFFu + ((u >> 16) & 1u)) >> 16;
}
__device__ __forceinline__ void split2(float a, float b, int& hi, int& lo) {
  unsigned ha = rne_bf16(a), hb = rne_bf16(b);
  float ra = a - __uint_as_float(ha << 16);
  float rb = b - __uint_as_float(hb << 16);
  hi = (int)(ha | (hb << 16));
  lo = (int)(rne_bf16(ra) | (rne_bf16(rb) << 16));
}
__device__ __forceinline__ void split8(const float* x, Frag& hi, Frag& lo) {
#pragma unroll
  for (int p = 0; p < 4; p++) split2(x[2 * p], x[2 * p + 1], hi.i[p], lo.i[p]);
}
__device__ __forceinline__ float ftanh(float x) {
  float e = __expf(2.0f * x);
  return 1.0f - 2.0f * __builtin_amdgcn_rcpf(e + 1.0f);
}
__device__ __forceinline__ f4 mf(const Frag& a, const Frag& b, f4 c) {
  return __builtin_amdgcn_mfma_f32_16x16x32_bf16(a.v, b.v, c, 0, 0, 0);
}
// Barrier with LDS-only drain: keeps global loads (vmcnt) in flight across steps.
__device__ __forceinline__ void lds_barrier() {
  __builtin_amdgcn_s_waitcnt(0xC07F);  // lgkmcnt(0), vmcnt=63, expcnt=7
  __builtin_amdgcn_s_barrier();
}
__device__ __forceinline__ void wfrag(const float* W, int row0, int c, int lane,
                                      Frag& hi, Frag& lo) {
  const int m = lane & 15, qq = lane >> 4;
  const f4* p = (const f4*)(W + (size_t)(row0 + m) * 192 + 32 * c + 8 * qq);
  f4 a = p[0], b = p[1];
  float t[8] = {a[0], a[1], a[2], a[3], b[0], b[1], b[2], b[3]};
  split8(t, hi, lo);
}

// ---- prep_w: build Wfull [192 x 192] fp32 ----
// rows 0..63 (x'): [A | B2 | B1 | 0]; 64..127 (z~'): [C2A | C2B2 | C2B1 | D21];
// 128..191 (y): [C1A | C1B2+D12 | C1B1+D11 | 0]
__global__ void prep_w(const float* __restrict__ A, const float* __restrict__ B1,
                       const float* __restrict__ B2, const float* __restrict__ C1,
                       const float* __restrict__ D11, const float* __restrict__ D12,
                       const float* __restrict__ C2, const float* __restrict__ D21,
                       float* __restrict__ Wfull) {
  const int r = blockIdx.x;   // 0..191
  const int c = threadIdx.x;  // 0..191
  float v = 0.f;
  if (c < 64) {
    const int j = c;
    if (r < 64) v = A[r * 64 + j];
    else if (r < 128) { float s = 0.f; for (int l = 0; l < 64; l++) s += C2[(r - 64) * 64 + l] * A[l * 64 + j]; v = s; }
    else { float s = 0.f; for (int l = 0; l < 64; l++) s += C1[(r - 128) * 64 + l] * A[l * 64 + j]; v = s; }
  } else if (c < 128) {
    const int j = c - 64;
    if (r < 64) v = B2[r * 64 + j];
    else if (r < 128) { float s = 0.f; for (int l = 0; l < 64; l++) s += C2[(r - 64) * 64 + l] * B2[l * 64 + j]; v = s; }
    else { float s = 0.f; for (int l = 0; l < 64; l++) s += C1[(r - 128) * 64 + l] * B2[l * 64 + j]; v = s + D12[(r - 128) * 64 + j]; }
  } else if (c < 160) {
    const int j = c - 128;
    if (r < 64) v = B1[r * 32 + j];
    else if (r < 128) { float s = 0.f; for (int l = 0; l < 64; l++) s += C2[(r - 64) * 64 + l] * B1[l * 32 + j]; v = s; }
    else { float s = 0.f; for (int l = 0; l < 64; l++) s += C1[(r - 128) * 64 + l] * B1[l * 32 + j]; v = s + D11[(r - 128) * 32 + j]; }
  } else {
    const int j = c - 160;
    v = (r >= 64 && r < 128) ? D21[(r - 64) * 32 + j] : 0.f;
  }
  Wfull[r * 192 + c] = v;
}

// ---- prep_uu: MFMA-based u-projection (R5, verified) ----
// UU[k][blk][tt:12][lane:64][4] in D-fragment order of mfma_f32_16x16x32:
//   tt 0..3: z rows 64+16t  (C2B1 u_k + D21 u_{k+1}; W cols 128..191, K=64)
//   tt 4..7: x rows 16t     (B1 u_k;                 W cols 128..159, K=32)
//   tt 8..11: y rows 128+16t ((C1B1+D11) u_k;        W cols 128..159, K=32)
__global__ __launch_bounds__(256)
void prep_uu(const float* __restrict__ us, const float* __restrict__ Wfull,
             float* __restrict__ UU) {
  const int blk = blockIdx.x;        // 0..7 (batch group of 16)
  const int kc = blockIdx.y;         // 0..63 (32 k each)
  const int wv = threadIdx.x >> 6;   // 0..3 (tile row-group)
  const int lane = threadIdx.x & 63;
  const int nn = lane & 15, q = lane >> 4;
  const int b0 = blk * 16;

  Frag zh4, zl4, zh5, zl5, xh4, xl4, yh4, yl4;
  wfrag(Wfull, 64 + 16 * wv, 4, lane, zh4, zl4);
  wfrag(Wfull, 64 + 16 * wv, 5, lane, zh5, zl5);
  wfrag(Wfull, 16 * wv, 4, lane, xh4, xl4);
  wfrag(Wfull, 128 + 16 * wv, 4, lane, yh4, yl4);

  const float* ubase = us + (size_t)(b0 + nn) * (NT * 32) + 8 * q;

  int k = kc * 32;
  Frag uhc, ulc, uhn, uln;
  {  // cur = u_k
    const f4* p = (const f4*)(ubase + (size_t)k * 32);
    f4 a = p[0], b = p[1];
    float t[8] = {a[0], a[1], a[2], a[3], b[0], b[1], b[2], b[3]};
    split8(t, uhc, ulc);
  }
  f4 ra, rb;
  {  // raw next = u_{k+1}
    const int kn = (k + 1 < NT) ? k + 1 : NT - 1;
    const f4* p = (const f4*)(ubase + (size_t)kn * 32);
    ra = p[0]; rb = p[1];
  }
  for (int k0 = 0; k0 < 32; k0++, k++) {
    {
      float t[8] = {ra[0], ra[1], ra[2], ra[3], rb[0], rb[1], rb[2], rb[3]};
      split8(t, uhn, uln);
    }
    {  // prefetch raw u_{k+2} (consumed next iteration; hides under MFMAs)
      const int kp = (k + 2 < NT) ? k + 2 : NT - 1;
      const f4* p = (const f4*)(ubase + (size_t)kp * 32);
      ra = p[0]; rb = p[1];
    }
    f4 az = {0.f, 0.f, 0.f, 0.f}, ax = az, ay = az;
    az = mf(zh4, uhc, az); az = mf(zh5, uhn, az);
    az = mf(zh4, ulc, az); az = mf(zh5, uln, az);
    az = mf(zl4, uhc, az); az = mf(zl5, uhn, az);
    ax = mf(xh4, uhc, ax); ax = mf(xh4, ulc, ax); ax = mf(xl4, uhc, ax);
    ay = mf(yh4, uhc, ay); ay = mf(yh4, ulc, ay); ay = mf(yl4, uhc, ay);
    float* dst = UU + ((size_t)k * 8 + blk) * 3072 + lane * 4;
    *(f4*)(dst + wv * 256) = az;
    *(f4*)(dst + (4 + wv) * 256) = ax;
    *(f4*)(dst + (8 + wv) * 256) = ay;
    uhc = uhn; ulc = uln;
  }
}

// ---- sequential recurrence: 8 blocks x 512 threads, 8 waves (1 tile each) ----
// LDS slots: 0,1 = x_hi c0,c1; 2,3 = x_lo; 4,5 = w_hi; 6,7 = w_lo.
// Slot = [4 groups x 70 dw] (stride 70 breaks the 4-lane/bank-quad pattern);
// reads are ds_read2_b64 pairs (2 lanes/bank-pair = conflict-free).
__global__ __launch_bounds__(512, 1)
void lure_seq8(const float* __restrict__ x0, const float* __restrict__ us,
               const float* __restrict__ C2, const float* __restrict__ D21,
               const float* __restrict__ Wfull, const float* __restrict__ UU,
               float* __restrict__ out) {
  __shared__ int lds[2][8][280];
  const int tid = threadIdx.x;
  const int wave = tid >> 6;
  const int lane = tid & 63;
  const int q = lane >> 4;
  const int nn = lane & 15;
  const int b0 = blockIdx.x * 16;
  const int ro = q * 70 + nn * 4;
  const size_t KSTRIDE = 8 * 12 * 256;  // floats per k

  // ---- prologue (first 4 waves): x_0 and w_0 into buffer 0 ----
  if (tid < 256) {
    const int n = tid >> 4;
    const int f0 = (tid & 15) * 4;
    const int cc = f0 >> 5;
    const int g = (f0 & 31) >> 3;
    const int d = (f0 & 7) >> 1;
    const int idx = g * 70 + n * 4 + d;
    const float* xrow = x0 + (b0 + n) * 64;
    float xv[4] = {xrow[f0], xrow[f0 + 1], xrow[f0 + 2], xrow[f0 + 3]};
    int h0, l0, h1, l1;
    split2(xv[0], xv[1], h0, l0);
    split2(xv[2], xv[3], h1, l1);
    lds[0][cc][idx] = h0;     lds[0][cc][idx + 1] = h1;
    lds[0][2 + cc][idx] = l0; lds[0][2 + cc][idx + 1] = l1;
    float zv[4] = {0.f, 0.f, 0.f, 0.f};
    for (int j = 0; j < 64; j++) {
      float xj = xrow[j];
#pragma unroll
      for (int r = 0; r < 4; r++) zv[r] += C2[(f0 + r) * 64 + j] * xj;
    }
    const float* urow = us + (size_t)(b0 + n) * (NT * 32);
    for (int j = 0; j < 32; j++) {
      float uj = urow[j];
#pragma unroll
      for (int r = 0; r < 4; r++) zv[r] += D21[(f0 + r) * 32 + j] * uj;
    }
#pragma unroll
    for (int r = 0; r < 4; r++) zv[r] = ftanh(zv[r]);
    split2(zv[0], zv[1], h0, l0);
    split2(zv[2], zv[3], h1, l1);
    lds[0][4 + cc][idx] = h0; lds[0][4 + cc][idx + 1] = h1;
    lds[0][6 + cc][idx] = l0; lds[0][6 + cc][idx + 1] = l1;
  }

  if (wave < 4) {
    // ---- z-wave: tile zt = wave, rows 64+16*zt, 4 K-chunks (x,w), 3-term ----
    const int zt = wave;
    Frag WH[4], WL[4];
#pragma unroll
    for (int c = 0; c < 4; c++) wfrag(Wfull, 64 + 16 * zt, c, lane, WH[c], WL[c]);
    const float* up = UU + (((size_t)blockIdx.x * 12 + zt) * 64 + lane) * 4;
    f4 uz[4];
#pragma unroll
    for (int d = 0; d < 4; d++) uz[d] = *(const f4*)(up + (size_t)d * KSTRIDE);
    const int widx = (2 * (zt & 1) + (q >> 1)) * 70 + nn * 4 + 2 * (q & 1);
    const int sh = 4 + (zt >> 1), sl = 6 + (zt >> 1);
    lds_barrier();

    auto zstep = [&](int kk, int d) {
      const int rb = kk & 1;
      Frag bh[4], bl[4];
#pragma unroll
      for (int c = 0; c < 4; c++) {
        const int s = (c < 2) ? c : 2 + c;
        bh[c].h[0] = *(const i2*)&lds[rb][s][ro];
        bh[c].h[1] = *(const i2*)&lds[rb][s][ro + 2];
        bl[c].h[0] = *(const i2*)&lds[rb][s + 2][ro];
        bl[c].h[1] = *(const i2*)&lds[rb][s + 2][ro + 2];
      }
      f4 s1 = uz[d];
      f4 s2 = {0.f, 0.f, 0.f, 0.f}, s3 = s2;
#pragma unroll
      for (int c = 0; c < 4; c++) {
        s1 = mf(WH[c], bh[c], s1);
        s2 = mf(WH[c], bl[c], s2);
        s3 = mf(WL[c], bh[c], s3);
      }
      const int kp = (kk + 4 < NT) ? kk + 4 : NT - 1;
      uz[d] = *(const f4*)(up + (size_t)kp * KSTRIDE);
      float wv[4];
#pragma unroll
      for (int r = 0; r < 4; r++) wv[r] = ftanh(s1[r] + s2[r] + s3[r]);
      int h0, l0, h1, l1;
      split2(wv[0], wv[1], h0, l0);
      split2(wv[2], wv[3], h1, l1);
      i2 wh; wh[0] = h0; wh[1] = h1;
      i2 wl; wl[0] = l0; wl[1] = l1;
      *(i2*)&lds[rb ^ 1][sh][widx] = wh;
      *(i2*)&lds[rb ^ 1][sl][widx] = wl;
      lds_barrier();
    };
    for (int k = 0; k < NT; k += 4) {
      zstep(k, 0); zstep(k + 1, 1); zstep(k + 2, 2); zstep(k + 3, 3);
    }
  } else {
    // ---- x-wave: x'-tile xt rows 16*xt (3-term) + y-tile rows 128+16*xt (1-term) ----
    const int xt = wave - 4;
    Frag WXH[4], WXL[4], WYH[4];
#pragma unroll
    for (int c = 0; c < 4; c++) {
      wfrag(Wfull, 16 * xt, c, lane, WXH[c], WXL[c]);
      Frag dmy;
      wfrag(Wfull, 128 + 16 * xt, c, lane, WYH[c], dmy);
    }
    const float* upx = UU + (((size_t)blockIdx.x * 12 + 4 + xt) * 64 + lane) * 4;
    const float* upy = UU + (((size_t)blockIdx.x * 12 + 8 + xt) * 64 + lane) * 4;
    f4 ux[4], uy[4];
#pragma unroll
    for (int d = 0; d < 4; d++) {
      ux[d] = *(const f4*)(upx + (size_t)d * KSTRIDE);
      uy[d] = *(const f4*)(upy + (size_t)d * KSTRIDE);
    }
    const int widx = (2 * (xt & 1) + (q >> 1)) * 70 + nn * 4 + 2 * (q & 1);
    const int sh = (xt >> 1), sl = 2 + (xt >> 1);
    float* py0 = out + (size_t)(b0 + nn) * (NT * 64) + 16 * xt + 4 * q;
    lds_barrier();

    auto xstep = [&](int kk, int d) {
      const int rb = kk & 1;
      Frag bh[4], bl[4];
#pragma unroll
      for (int c = 0; c < 4; c++) {
        const int s = (c < 2) ? c : 2 + c;
        bh[c].h[0] = *(const i2*)&lds[rb][s][ro];
        bh[c].h[1] = *(const i2*)&lds[rb][s][ro + 2];
        bl[c].h[0] = *(const i2*)&lds[rb][s + 2][ro];
        bl[c].h[1] = *(const i2*)&lds[rb][s + 2][ro + 2];
      }
      f4 s1 = ux[d], sy = uy[d];
      f4 s2 = {0.f, 0.f, 0.f, 0.f}, s3 = s2;
#pragma unroll
      for (int c = 0; c < 4; c++) {
        s1 = mf(WXH[c], bh[c], s1);
        s2 = mf(WXH[c], bl[c], s2);
        s3 = mf(WXL[c], bh[c], s3);
        sy = mf(WYH[c], bh[c], sy);
      }
      const int kp = (kk + 4 < NT) ? kk + 4 : NT - 1;
      ux[d] = *(const f4*)(upx + (size_t)kp * KSTRIDE);
      uy[d] = *(const f4*)(upy + (size_t)kp * KSTRIDE);
      float xv[4];
#pragma unroll
      for (int r = 0; r < 4; r++) xv[r] = s1[r] + s2[r] + s3[r];
      int h0, l0, h1, l1;
      split2(xv[0], xv[1], h0, l0);
      split2(xv[2], xv[3], h1, l1);
      i2 wh; wh[0] = h0; wh[1] = h1;
      i2 wl; wl[0] = l0; wl[1] = l1;
      *(i2*)&lds[rb ^ 1][sh][widx] = wh;
      *(i2*)&lds[rb ^ 1][sl][widx] = wl;
      *(f4*)(py0 + (size_t)kk * 64) = sy;
      lds_barrier();
    };
    for (int k = 0; k < NT; k += 4) {
      xstep(k, 0); xstep(k + 1, 1); xstep(k + 2, 2); xstep(k + 3, 3);
    }
  }
}

// ---- fallback (ws too small for UU): R3's 4-wave kernel, Wfull only ----
__global__ __launch_bounds__(256, 1)
void lure_seq_fb(const float* __restrict__ x0, const float* __restrict__ us,
                 const float* __restrict__ C2, const float* __restrict__ D21,
                 const float* __restrict__ Wfull, float* __restrict__ out) {
  __shared__ int lds[2][8][272];
  const int tid = threadIdx.x;
  const int wave = tid >> 6;
  const int lane = tid & 63;
  const int q = lane >> 4;
  const int nn = lane & 15;
  const int b0 = blockIdx.x * 16;
  const int ro = q * 68 + nn * 4;
  {
    const int n = tid >> 4;
    const int f0 = (tid & 15) * 4;
    const int cc = f0 >> 5;
    const int g = (f0 & 31) >> 3;
    const int d = (f0 & 7) >> 1;
    const int idx = g * 68 + n * 4 + d;
    const float* xrow = x0 + (b0 + n) * 64;
    float xv[4] = {xrow[f0], xrow[f0 + 1], xrow[f0 + 2], xrow[f0 + 3]};
    int h0, l0, h1, l1;
    split2(xv[0], xv[1], h0, l0);
    split2(xv[2], xv[3], h1, l1);
    lds[0][cc][idx] = h0;     lds[0][cc][idx + 1] = h1;
    lds[0][2 + cc][idx] = l0; lds[0][2 + cc][idx + 1] = l1;
    float zv[4] = {0.f, 0.f, 0.f, 0.f};
    for (int j = 0; j < 64; j++) {
      float xj = xrow[j];
#pragma unroll
      for (int r = 0; r < 4; r++) zv[r] += C2[(f0 + r) * 64 + j] * xj;
    }
    const float* urow = us + (size_t)(b0 + n) * (NT * 32);
    for (int j = 0; j < 32; j++) {
      float uj = urow[j];
#pragma unroll
      for (int r = 0; r < 4; r++) zv[r] += D21[(f0 + r) * 32 + j] * uj;
    }
#pragma unroll
    for (int r = 0; r < 4; r++) zv[r] = ftanh(zv[r]);
    split2(zv[0], zv[1], h0, l0);
    split2(zv[2], zv[3], h1, l1);
    lds[0][4 + cc][idx] = h0; lds[0][4 + cc][idx + 1] = h1;
    lds[0][6 + cc][idx] = l0; lds[0][6 + cc][idx + 1] = l1;
  }
  Frag uh[2], ul[2];
  f4 ra0[4], ra1[4];
  const float* pu = us + ((size_t)(b0 + nn) * NT) * 32 + 8 * q;
#pragma unroll
  for (int j = 0; j < 2; j++) {
    const f4* p = (const f4*)(pu + j * 32);
    f4 a = p[0], b = p[1];
    float t[8] = {a[0], a[1], a[2], a[3], b[0], b[1], b[2], b[3]};
    split8(t, uh[j], ul[j]);
  }
#pragma unroll
  for (int j = 2; j <= 5; j++) {
    const f4* p = (const f4*)(pu + j * 32);
    ra0[j & 3] = p[0];
    ra1[j & 3] = p[1];
  }
  lds_barrier();

  if (wave < 2) {
    const int Z0 = wave * 2;
    Frag WH[2][6], WL[2][6];
#pragma unroll
    for (int t = 0; t < 2; t++)
#pragma unroll
      for (int c = 0; c < 6; c++)
        wfrag(Wfull, 64 + 16 * (Z0 + t), c, lane, WH[t][c], WL[t][c]);
    auto zstep = [&](int kk, int uu) {
      const int rb = uu & 1;
      Frag bh[4], bl[4];
#pragma unroll
      for (int c = 0; c < 4; c++) {
        const int s = (c < 2) ? c : 2 + c;
        bh[c].v = *(const short8*)&lds[rb][s][ro];
        bl[c].v = *(const short8*)&lds[rb][s + 2][ro];
      }
      const int i4 = uu & 1, i5 = (uu + 1) & 1;
#pragma unroll
      for (int t = 0; t < 2; t++) {
        f4 z4 = {0.f, 0.f, 0.f, 0.f};
        f4 s1a = z4, s1b = z4, s2a = z4, s2b = z4, s3a = z4, s3b = z4;
        s1a = mf(WH[t][0], bh[0], s1a); s1b = mf(WH[t][1], bh[1], s1b);
        s2a = mf(WH[t][0], bl[0], s2a); s2b = mf(WH[t][1], bl[1], s2b);
        s3a = mf(WL[t][0], bh[0], s3a); s3b = mf(WL[t][1], bh[1], s3b);
        s1a = mf(WH[t][2], bh[2], s1a); s1b = mf(WH[t][3], bh[3], s1b);
        s2a = mf(WH[t][2], bl[2], s2a); s2b = mf(WH[t][3], bl[3], s2b);
        s3a = mf(WL[t][2], bh[2], s3a); s3b = mf(WL[t][3], bh[3], s3b);
        s1a = mf(WH[t][4], uh[i4], s1a); s1b = mf(WH[t][5], uh[i5], s1b);
        s2a = mf(WH[t][4], ul[i4], s2a); s2b = mf(WH[t][5], ul[i5], s2b);
        s3a = mf(WL[t][4], uh[i4], s3a); s3b = mf(WL[t][5], uh[i5], s3b);
        float wv[4];
#pragma unroll
        for (int r = 0; r < 4; r++)
          wv[r] = ftanh(((s1a[r] + s1b[r]) + (s2a[r] + s2b[r])) + (s3a[r] + s3b[r]));
        int h0, l0, h1, l1;
        split2(wv[0], wv[1], h0, l0);
        split2(wv[2], wv[3], h1, l1);
        const int zt = Z0 + t;
        const int widx = (2 * (zt & 1) + (q >> 1)) * 68 + nn * 4 + 2 * (q & 1);
        i2 wh; wh[0] = h0; wh[1] = h1;
        i2 wl; wl[0] = l0; wl[1] = l1;
        *(i2*)&lds[rb ^ 1][4 + (zt >> 1)][widx] = wh;
        *(i2*)&lds[rb ^ 1][6 + (zt >> 1)][widx] = wl;
      }
      f4 a = ra0[(uu + 2) & 3], b = ra1[(uu + 2) & 3];
      float t8[8] = {a[0], a[1], a[2], a[3], b[0], b[1], b[2], b[3]};
      split8(t8, uh[uu & 1], ul[uu & 1]);
      const int kp = (kk + 6 < NT) ? kk + 6 : NT - 1;
      const f4* p = (const f4*)(pu + (size_t)kp * 32);
      ra0[(uu + 2) & 3] = p[0];
      ra1[(uu + 2) & 3] = p[1];
      lds_barrier();
    };
    for (int k = 0; k < NT; k += 4) {
      zstep(k, 0); zstep(k + 1, 1); zstep(k + 2, 2); zstep(k + 3, 3);
    }
  } else {
    const int X0 = (wave - 2) * 2;
    Frag WXH[2][5], WXL[2][5], WYH[2][5];
#pragma unroll
    for (int t = 0; t < 2; t++)
#pragma unroll
      for (int c = 0; c < 5; c++) {
        wfrag(Wfull, 16 * (X0 + t), c, lane, WXH[t][c], WXL[t][c]);
        Frag dmy;
        wfrag(Wfull, 128 + 16 * (X0 + t), c, lane, WYH[t][c], dmy);
      }
    float* py0 = out + (size_t)(b0 + nn) * (NT * 64) + 16 * X0 + 4 * q;
    auto xstep = [&](int kk, int uu) {
      const int rb = uu & 1;
      Frag bh[4], bl[4];
#pragma unroll
      for (int c = 0; c < 4; c++) {
        const int s = (c < 2) ? c : 2 + c;
        bh[c].v = *(const short8*)&lds[rb][s][ro];
        bl[c].v = *(const short8*)&lds[rb][s + 2][ro];
      }
      const int i4 = uu & 1;
#pragma unroll
      for (int t = 0; t < 2; t++) {
        f4 z4 = {0.f, 0.f, 0.f, 0.f};
        f4 s1 = z4, s2 = z4, s3 = z4, sy = z4;
#pragma unroll
        for (int c = 0; c < 4; c++) {
          s1 = mf(WXH[t][c], bh[c], s1);
          s2 = mf(WXH[t][c], bl[c], s2);
          s3 = mf(WXL[t][c], bh[c], s3);
          sy = mf(WYH[t][c], bh[c], sy);
        }
        s1 = mf(WXH[t][4], uh[i4], s1);
        s2 = mf(WXH[t][4], ul[i4], s2);
        s3 = mf(WXL[t][4], uh[i4], s3);
        sy = mf(WYH[t][4], uh[i4], sy);
        float xv[4];
#pragma unroll
        for (int r = 0; r < 4; r++) xv[r] = s1[r] + s2[r] + s3[r];
        int h0, l0, h1, l1;
        split2(xv[0], xv[1], h0, l0);
        split2(xv[2], xv[3], h1, l1);
        const int xt = X0 + t;
        const int widx = (2 * (xt & 1) + (q >> 1)) * 68 + nn * 4 + 2 * (q & 1);
        i2 wh; wh[0] = h0; wh[1] = h1;
        i2 wl; wl[0] = l0; wl[1] = l1;
        *(i2*)&lds[rb ^ 1][(xt >> 1)][widx] = wh;
        *(i2*)&lds[rb ^ 1][2 + (xt >> 1)][widx] = wl;
        *(f4*)(py0 + (size_t)kk * 64 + 16 * t) = sy;
      }
      f4 a = ra0[(uu + 2) & 3], b = ra1[(uu + 2) & 3];
      float t8[8] = {a[0], a[1], a[2], a[3], b[0], b[1], b[2], b[3]};
      split8(t8, uh[uu & 1], ul[uu & 1]);
      const int kp = (kk + 6 < NT) ? kk + 6 : NT - 1;
      const f4* p = (const f4*)(pu + (size_t)kp * 32);
      ra0[(uu + 2) & 3] = p[0];
      ra1[(uu + 2) & 3] = p[1];
      lds_barrier();
    };
    for (int k = 0; k < NT; k += 4) {
      xstep(k, 0); xstep(k + 1, 1); xstep(k + 2, 2); xstep(k + 3, 3);
    }
  }
}

extern "C" void kernel_launch(void* const* d_in, const int* in_sizes, int n_in,
                              void* d_out, int out_size, void* d_ws, size_t ws_size,
                              hipStream_t stream) {
  const float* x0  = (const float*)d_in[0];
  const float* us  = (const float*)d_in[1];
  const float* A   = (const float*)d_in[2];
  const float* B1  = (const float*)d_in[3];
  const float* B2  = (const float*)d_in[4];
  const float* C1  = (const float*)d_in[5];
  const float* D11 = (const float*)d_in[6];
  const float* D12 = (const float*)d_in[7];
  const float* C2  = (const float*)d_in[8];
  const float* D21 = (const float*)d_in[9];
  float* Wfull = (float*)d_ws;  // 147456 bytes
  const size_t W_BYTES = (size_t)192 * 192 * 4;
  float* UU = (float*)((char*)d_ws + W_BYTES);
  const size_t UU_BYTES = (size_t)NT * 8 * 12 * 256 * 4;  // 201.3 MB
  const bool pre = ws_size >= W_BYTES + UU_BYTES;
  float* out = (float*)d_out;

  prep_w<<<dim3(192), dim3(192), 0, stream>>>(A, B1, B2, C1, D11, D12, C2, D21, Wfull);
  if (pre) {
    prep_uu<<<dim3(8, 64), dim3(256), 0, stream>>>(us, Wfull, UU);
    lure_seq8<<<dim3(8), dim3(512), 0, stream>>>(x0, us, C2, D21, Wfull, UU, out);
  } else {
    lure_seq_fb<<<dim3(8), dim3(256), 0, stream>>>(x0, us, C2, D21, Wfull, out);
  }
}

// Round 5
// 1005.082 us; speedup vs baseline: 1.5141x; 1.5141x over previous
//
#include <hip/hip_runtime.h>

// Lure RNN, latency-bound sequential chain.
// R8: batch-8 packed blocks. 16 blocks x 8 batches; LDS B-operand packs state
// hi in MFMA cols 0-7 and lo in cols 8-15, so ONE b128 read feeds both the
// main and the lo-correction product, and ONE MFMA (A=WH) computes s1|s2 in
// disjoint output columns. s2 reaches lanes 0-7 via v_mov_dpp row_ror:8
// (VALU, no LDS). Per CU: ds_read_b128 64->32 per step, MFMA 28->20 per SIMD.
// Arithmetic identical to R4's verified 3-term scheme. R7 lesson: LDS wide-op
// phases (8 lanes for b128) were already conflict-free in R4; the counter
// includes inherent serialization, so layout tweaks were chasing a phantom.
// prep_w/prep_uu = R5-exact (verified).

#define NT 2048

typedef __attribute__((ext_vector_type(8))) short short8;
typedef __attribute__((ext_vector_type(4))) float f4;
typedef __attribute__((ext_vector_type(2))) int i2;

union Frag { int i[4]; i2 h[2]; short8 v; };

__device__ __forceinline__ unsigned rne_bf16(float f) {
  unsigned u = __float_as_uint(f);
  return (u + 0x7FFFu + ((u >> 16) & 1u)) >> 16;
}
__device__ __forceinline__ void split2(float a, float b, int& hi, int& lo) {
  unsigned ha = rne_bf16(a), hb = rne_bf16(b);
  float ra = a - __uint_as_float(ha << 16);
  float rb = b - __uint_as_float(hb << 16);
  hi = (int)(ha | (hb << 16));
  lo = (int)(rne_bf16(ra) | (rne_bf16(rb) << 16));
}
__device__ __forceinline__ void split8(const float* x, Frag& hi, Frag& lo) {
#pragma unroll
  for (int p = 0; p < 4; p++) split2(x[2 * p], x[2 * p + 1], hi.i[p], lo.i[p]);
}
__device__ __forceinline__ float ftanh(float x) {
  float e = __expf(2.0f * x);
  return 1.0f - 2.0f * __builtin_amdgcn_rcpf(e + 1.0f);
}
__device__ __forceinline__ f4 mf(const Frag& a, const Frag& b, f4 c) {
  return __builtin_amdgcn_mfma_f32_16x16x32_bf16(a.v, b.v, c, 0, 0, 0);
}
// lane <- lane^8 within each 16-lane row (VALU DPP, no LDS pipe)
__device__ __forceinline__ float ror8f(float x) {
  return __int_as_float(
      __builtin_amdgcn_mov_dpp(__float_as_int(x), 0x128, 0xf, 0xf, true));
}
// Barrier with LDS-only drain: keeps global loads (vmcnt) in flight across steps.
__device__ __forceinline__ void lds_barrier() {
  __builtin_amdgcn_s_waitcnt(0xC07F);  // lgkmcnt(0), vmcnt=63, expcnt=7
  __builtin_amdgcn_s_barrier();
}
__device__ __forceinline__ void wfrag(const float* W, int row0, int c, int lane,
                                      Frag& hi, Frag& lo) {
  const int m = lane & 15, qq = lane >> 4;
  const f4* p = (const f4*)(W + (size_t)(row0 + m) * 192 + 32 * c + 8 * qq);
  f4 a = p[0], b = p[1];
  float t[8] = {a[0], a[1], a[2], a[3], b[0], b[1], b[2], b[3]};
  split8(t, hi, lo);
}

// ---- prep_w: build Wfull [192 x 192] fp32 ----
// rows 0..63 (x'): [A | B2 | B1 | 0]; 64..127 (z~'): [C2A | C2B2 | C2B1 | D21];
// 128..191 (y): [C1A | C1B2+D12 | C1B1+D11 | 0]
__global__ void prep_w(const float* __restrict__ A, const float* __restrict__ B1,
                       const float* __restrict__ B2, const float* __restrict__ C1,
                       const float* __restrict__ D11, const float* __restrict__ D12,
                       const float* __restrict__ C2, const float* __restrict__ D21,
                       float* __restrict__ Wfull) {
  const int r = blockIdx.x;   // 0..191
  const int c = threadIdx.x;  // 0..191
  float v = 0.f;
  if (c < 64) {
    const int j = c;
    if (r < 64) v = A[r * 64 + j];
    else if (r < 128) { float s = 0.f; for (int l = 0; l < 64; l++) s += C2[(r - 64) * 64 + l] * A[l * 64 + j]; v = s; }
    else { float s = 0.f; for (int l = 0; l < 64; l++) s += C1[(r - 128) * 64 + l] * A[l * 64 + j]; v = s; }
  } else if (c < 128) {
    const int j = c - 64;
    if (r < 64) v = B2[r * 64 + j];
    else if (r < 128) { float s = 0.f; for (int l = 0; l < 64; l++) s += C2[(r - 64) * 64 + l] * B2[l * 64 + j]; v = s; }
    else { float s = 0.f; for (int l = 0; l < 64; l++) s += C1[(r - 128) * 64 + l] * B2[l * 64 + j]; v = s + D12[(r - 128) * 64 + j]; }
  } else if (c < 160) {
    const int j = c - 128;
    if (r < 64) v = B1[r * 32 + j];
    else if (r < 128) { float s = 0.f; for (int l = 0; l < 64; l++) s += C2[(r - 64) * 64 + l] * B1[l * 32 + j]; v = s; }
    else { float s = 0.f; for (int l = 0; l < 64; l++) s += C1[(r - 128) * 64 + l] * B1[l * 32 + j]; v = s + D11[(r - 128) * 32 + j]; }
  } else {
    const int j = c - 160;
    v = (r >= 64 && r < 128) ? D21[(r - 64) * 32 + j] : 0.f;
  }
  Wfull[r * 192 + c] = v;
}

// ---- prep_uu: MFMA-based u-projection (R5, verified) ----
// UU[k][blk:8][tt:12][lane:64][4] in D-fragment order of mfma_f32_16x16x32:
//   tt 0..3: z rows 64+16t  (C2B1 u_k + D21 u_{k+1}; W cols 128..191, K=64)
//   tt 4..7: x rows 16t     (B1 u_k;                 W cols 128..159, K=32)
//   tt 8..11: y rows 128+16t ((C1B1+D11) u_k;        W cols 128..159, K=32)
__global__ __launch_bounds__(256)
void prep_uu(const float* __restrict__ us, const float* __restrict__ Wfull,
             float* __restrict__ UU) {
  const int blk = blockIdx.x;        // 0..7 (batch group of 16)
  const int kc = blockIdx.y;         // 0..63 (32 k each)
  const int wv = threadIdx.x >> 6;   // 0..3 (tile row-group)
  const int lane = threadIdx.x & 63;
  const int nn = lane & 15, q = lane >> 4;
  const int b0 = blk * 16;

  Frag zh4, zl4, zh5, zl5, xh4, xl4, yh4, yl4;
  wfrag(Wfull, 64 + 16 * wv, 4, lane, zh4, zl4);
  wfrag(Wfull, 64 + 16 * wv, 5, lane, zh5, zl5);
  wfrag(Wfull, 16 * wv, 4, lane, xh4, xl4);
  wfrag(Wfull, 128 + 16 * wv, 4, lane, yh4, yl4);

  const float* ubase = us + (size_t)(b0 + nn) * (NT * 32) + 8 * q;

  int k = kc * 32;
  Frag uhc, ulc, uhn, uln;
  {  // cur = u_k
    const f4* p = (const f4*)(ubase + (size_t)k * 32);
    f4 a = p[0], b = p[1];
    float t[8] = {a[0], a[1], a[2], a[3], b[0], b[1], b[2], b[3]};
    split8(t, uhc, ulc);
  }
  f4 ra, rb;
  {  // raw next = u_{k+1}
    const int kn = (k + 1 < NT) ? k + 1 : NT - 1;
    const f4* p = (const f4*)(ubase + (size_t)kn * 32);
    ra = p[0]; rb = p[1];
  }
  for (int k0 = 0; k0 < 32; k0++, k++) {
    {
      float t[8] = {ra[0], ra[1], ra[2], ra[3], rb[0], rb[1], rb[2], rb[3]};
      split8(t, uhn, uln);
    }
    {  // prefetch raw u_{k+2}
      const int kp = (k + 2 < NT) ? k + 2 : NT - 1;
      const f4* p = (const f4*)(ubase + (size_t)kp * 32);
      ra = p[0]; rb = p[1];
    }
    f4 az = {0.f, 0.f, 0.f, 0.f}, ax = az, ay = az;
    az = mf(zh4, uhc, az); az = mf(zh5, uhn, az);
    az = mf(zh4, ulc, az); az = mf(zh5, uln, az);
    az = mf(zl4, uhc, az); az = mf(zl5, uhn, az);
    ax = mf(xh4, uhc, ax); ax = mf(xh4, ulc, ax); ax = mf(xl4, uhc, ax);
    ay = mf(yh4, uhc, ay); ay = mf(yh4, ulc, ay); ay = mf(yl4, uhc, ay);
    float* dst = UU + ((size_t)k * 8 + blk) * 3072 + lane * 4;
    *(f4*)(dst + wv * 256) = az;
    *(f4*)(dst + (4 + wv) * 256) = ax;
    *(f4*)(dst + (8 + wv) * 256) = ay;
    uhc = uhn; ulc = uln;
  }
}

// ---- sequential recurrence (R8): 16 blocks x 512 threads, 8 batches each ----
// LDS regions per buffer: 0,1 = x chunks (K 0-31, 32-63); 2,3 = w chunks.
// Region layout: [4 k-groups x 68 dw]; within a group, dw nn*4: nn<8 = hi of
// batch nn, nn>=8 = lo of batch nn-8. Reader ro identical to R4 (proven
// conflict-free phases). One b128 read feeds hi (MFMA cols 0-7) and lo
// (cols 8-15) simultaneously.
__global__ __launch_bounds__(512, 1)
void lure_seqp(const float* __restrict__ x0, const float* __restrict__ us,
               const float* __restrict__ C2, const float* __restrict__ D21,
               const float* __restrict__ Wfull, const float* __restrict__ UU,
               float* __restrict__ out) {
  __shared__ int lds[2][4][272];
  const int tid = threadIdx.x;
  const int wave = tid >> 6;
  const int lane = tid & 63;
  const int q = lane >> 4;
  const int nn = lane & 15;
  const int b8 = blockIdx.x * 8;
  const int ro = q * 68 + nn * 4;
  const size_t KSTRIDE = 8 * 12 * 256;  // floats per k in UU
  const int ob = blockIdx.x >> 1, hh = blockIdx.x & 1;
  const int ulane = 8 * hh + (lane & 7) + 16 * q;  // UU lane remap (8-batch)
  const float msk = (lane & 8) ? 0.f : 1.f;        // valid-column mask

  // ---- prologue (threads 0..127): x_0 and w_0 packed into buffer 0 ----
  if (tid < 128) {
    const int n = tid >> 4;          // batch 0..7
    const int f0 = (tid & 15) * 4;   // rows f0..f0+3
    const int c = f0 >> 5;           // chunk
    const int g = (f0 & 31) >> 3;    // k-group
    const int d = (f0 & 7) >> 1;     // dw offset
    const int idx = g * 68 + n * 4 + d;
    const float* xrow = x0 + (b8 + n) * 64;
    float xv[4] = {xrow[f0], xrow[f0 + 1], xrow[f0 + 2], xrow[f0 + 3]};
    int h0, l0, h1, l1;
    split2(xv[0], xv[1], h0, l0);
    split2(xv[2], xv[3], h1, l1);
    lds[0][c][idx] = h0;       lds[0][c][idx + 1] = h1;
    lds[0][c][idx + 32] = l0;  lds[0][c][idx + 33] = l1;
    float zv[4] = {0.f, 0.f, 0.f, 0.f};
    for (int j = 0; j < 64; j++) {
      float xj = xrow[j];
#pragma unroll
      for (int r = 0; r < 4; r++) zv[r] += C2[(f0 + r) * 64 + j] * xj;
    }
    const float* urow = us + (size_t)(b8 + n) * (NT * 32);
    for (int j = 0; j < 32; j++) {
      float uj = urow[j];
#pragma unroll
      for (int r = 0; r < 4; r++) zv[r] += D21[(f0 + r) * 32 + j] * uj;
    }
#pragma unroll
    for (int r = 0; r < 4; r++) zv[r] = ftanh(zv[r]);
    split2(zv[0], zv[1], h0, l0);
    split2(zv[2], zv[3], h1, l1);
    lds[0][2 + c][idx] = h0;       lds[0][2 + c][idx + 1] = h1;
    lds[0][2 + c][idx + 32] = l0;  lds[0][2 + c][idx + 33] = l1;
  }

  if (wave < 4) {
    // ---- z-wave: rows 64+16*zt. Fused s1|s2 MFMA (A=WH) + s3 (A=WL). ----
    const int zt = wave;
    Frag WH[4], WL[4];
#pragma unroll
    for (int c = 0; c < 4; c++) wfrag(Wfull, 64 + 16 * zt, c, lane, WH[c], WL[c]);
    const float* up = UU + (((size_t)ob * 12 + zt) * 64 + ulane) * 4;
    f4 uz[4];
#pragma unroll
    for (int d = 0; d < 4; d++) uz[d] = *(const f4*)(up + (size_t)d * KSTRIDE);
    const int widx = (2 * (zt & 1) + (q >> 1)) * 68 + nn * 4 + 2 * (q & 1);
    const int rw = 2 + (zt >> 1);
    lds_barrier();

    auto zstep = [&](int kk, int d) {
      const int rb = kk & 1;
      Frag b[4];
#pragma unroll
      for (int c = 0; c < 4; c++) b[c].v = *(const short8*)&lds[rb][c][ro];
      f4 sA = {uz[d][0] * msk, uz[d][1] * msk, uz[d][2] * msk, uz[d][3] * msk};
      f4 sB = {0.f, 0.f, 0.f, 0.f};
#pragma unroll
      for (int c = 0; c < 4; c++) {
        sA = mf(WH[c], b[c], sA);   // cols 0-7: s1 (hi); cols 8-15: s2 (lo)
        sB = mf(WL[c], b[c], sB);   // cols 0-7: s3
      }
      const int kp = (kk + 4 < NT) ? kk + 4 : NT - 1;
      uz[d] = *(const f4*)(up + (size_t)kp * KSTRIDE);
      float wv[4];
#pragma unroll
      for (int r = 0; r < 4; r++) wv[r] = ftanh(sA[r] + ror8f(sA[r]) + sB[r]);
      int h0, l0, h1, l1;
      split2(wv[0], wv[1], h0, l0);
      split2(wv[2], wv[3], h1, l1);
      if ((lane & 8) == 0) {
        i2 wh; wh[0] = h0; wh[1] = h1;
        i2 wl; wl[0] = l0; wl[1] = l1;
        *(i2*)&lds[rb ^ 1][rw][widx] = wh;
        *(i2*)&lds[rb ^ 1][rw][widx + 32] = wl;
      }
      lds_barrier();
    };
    for (int k = 0; k < NT; k += 4) {
      zstep(k, 0); zstep(k + 1, 1); zstep(k + 2, 2); zstep(k + 3, 3);
    }
  } else {
    // ---- x-wave: x'-tile (fused t1|t2 + t3) + y-tile (1-term) ----
    const int xt = wave - 4;
    Frag WXH[4], WXL[4], WYH[4];
#pragma unroll
    for (int c = 0; c < 4; c++) {
      wfrag(Wfull, 16 * xt, c, lane, WXH[c], WXL[c]);
      Frag dmy;
      wfrag(Wfull, 128 + 16 * xt, c, lane, WYH[c], dmy);
    }
    const float* upx = UU + (((size_t)ob * 12 + 4 + xt) * 64 + ulane) * 4;
    const float* upy = UU + (((size_t)ob * 12 + 8 + xt) * 64 + ulane) * 4;
    f4 ux[4], uy[4];
#pragma unroll
    for (int d = 0; d < 4; d++) {
      ux[d] = *(const f4*)(upx + (size_t)d * KSTRIDE);
      uy[d] = *(const f4*)(upy + (size_t)d * KSTRIDE);
    }
    const int widx = (2 * (xt & 1) + (q >> 1)) * 68 + nn * 4 + 2 * (q & 1);
    const int rw = (xt >> 1);
    float* py0 = out + (size_t)(b8 + nn) * (NT * 64) + 16 * xt + 4 * q;
    lds_barrier();

    auto xstep = [&](int kk, int d) {
      const int rb = kk & 1;
      Frag b[4];
#pragma unroll
      for (int c = 0; c < 4; c++) b[c].v = *(const short8*)&lds[rb][c][ro];
      f4 tA = {ux[d][0] * msk, ux[d][1] * msk, ux[d][2] * msk, ux[d][3] * msk};
      f4 tB = {0.f, 0.f, 0.f, 0.f};
      f4 sy = uy[d];
#pragma unroll
      for (int c = 0; c < 4; c++) {
        tA = mf(WXH[c], b[c], tA);  // cols 0-7: t1; cols 8-15: t2
        tB = mf(WXL[c], b[c], tB);  // cols 0-7: t3
        sy = mf(WYH[c], b[c], sy);  // cols 0-7: y
      }
      const int kp = (kk + 4 < NT) ? kk + 4 : NT - 1;
      ux[d] = *(const f4*)(upx + (size_t)kp * KSTRIDE);
      uy[d] = *(const f4*)(upy + (size_t)kp * KSTRIDE);
      float xv[4];
#pragma unroll
      for (int r = 0; r < 4; r++) xv[r] = tA[r] + ror8f(tA[r]) + tB[r];
      int h0, l0, h1, l1;
      split2(xv[0], xv[1], h0, l0);
      split2(xv[2], xv[3], h1, l1);
      if ((lane & 8) == 0) {
        i2 wh; wh[0] = h0; wh[1] = h1;
        i2 wl; wl[0] = l0; wl[1] = l1;
        *(i2*)&lds[rb ^ 1][rw][widx] = wh;
        *(i2*)&lds[rb ^ 1][rw][widx + 32] = wl;
        *(f4*)(py0 + (size_t)kk * 64) = sy;
      }
      lds_barrier();
    };
    for (int k = 0; k < NT; k += 4) {
      xstep(k, 0); xstep(k + 1, 1); xstep(k + 2, 2); xstep(k + 3, 3);
    }
  }
}

// ---- fallback (ws too small for UU): R3's 4-wave kernel, Wfull only ----
__global__ __launch_bounds__(256, 1)
void lure_seq_fb(const float* __restrict__ x0, const float* __restrict__ us,
                 const float* __restrict__ C2, const float* __restrict__ D21,
                 const float* __restrict__ Wfull, float* __restrict__ out) {
  __shared__ int lds[2][8][272];
  const int tid = threadIdx.x;
  const int wave = tid >> 6;
  const int lane = tid & 63;
  const int q = lane >> 4;
  const int nn = lane & 15;
  const int b0 = blockIdx.x * 16;
  const int ro = q * 68 + nn * 4;
  {
    const int n = tid >> 4;
    const int f0 = (tid & 15) * 4;
    const int cc = f0 >> 5;
    const int g = (f0 & 31) >> 3;
    const int d = (f0 & 7) >> 1;
    const int idx = g * 68 + n * 4 + d;
    const float* xrow = x0 + (b0 + n) * 64;
    float xv[4] = {xrow[f0], xrow[f0 + 1], xrow[f0 + 2], xrow[f0 + 3]};
    int h0, l0, h1, l1;
    split2(xv[0], xv[1], h0, l0);
    split2(xv[2], xv[3], h1, l1);
    lds[0][cc][idx] = h0;     lds[0][cc][idx + 1] = h1;
    lds[0][2 + cc][idx] = l0; lds[0][2 + cc][idx + 1] = l1;
    float zv[4] = {0.f, 0.f, 0.f, 0.f};
    for (int j = 0; j < 64; j++) {
      float xj = xrow[j];
#pragma unroll
      for (int r = 0; r < 4; r++) zv[r] += C2[(f0 + r) * 64 + j] * xj;
    }
    const float* urow = us + (size_t)(b0 + n) * (NT * 32);
    for (int j = 0; j < 32; j++) {
      float uj = urow[j];
#pragma unroll
      for (int r = 0; r < 4; r++) zv[r] += D21[(f0 + r) * 32 + j] * uj;
    }
#pragma unroll
    for (int r = 0; r < 4; r++) zv[r] = ftanh(zv[r]);
    split2(zv[0], zv[1], h0, l0);
    split2(zv[2], zv[3], h1, l1);
    lds[0][4 + cc][idx] = h0; lds[0][4 + cc][idx + 1] = h1;
    lds[0][6 + cc][idx] = l0; lds[0][6 + cc][idx + 1] = l1;
  }
  Frag uh[2], ul[2];
  f4 ra0[4], ra1[4];
  const float* pu = us + ((size_t)(b0 + nn) * NT) * 32 + 8 * q;
#pragma unroll
  for (int j = 0; j < 2; j++) {
    const f4* p = (const f4*)(pu + j * 32);
    f4 a = p[0], b = p[1];
    float t[8] = {a[0], a[1], a[2], a[3], b[0], b[1], b[2], b[3]};
    split8(t, uh[j], ul[j]);
  }
#pragma unroll
  for (int j = 2; j <= 5; j++) {
    const f4* p = (const f4*)(pu + j * 32);
    ra0[j & 3] = p[0];
    ra1[j & 3] = p[1];
  }
  lds_barrier();

  if (wave < 2) {
    const int Z0 = wave * 2;
    Frag WH[2][6], WL[2][6];
#pragma unroll
    for (int t = 0; t < 2; t++)
#pragma unroll
      for (int c = 0; c < 6; c++)
        wfrag(Wfull, 64 + 16 * (Z0 + t), c, lane, WH[t][c], WL[t][c]);
    auto zstep = [&](int kk, int uu) {
      const int rb = uu & 1;
      Frag bh[4], bl[4];
#pragma unroll
      for (int c = 0; c < 4; c++) {
        const int s = (c < 2) ? c : 2 + c;
        bh[c].v = *(const short8*)&lds[rb][s][ro];
        bl[c].v = *(const short8*)&lds[rb][s + 2][ro];
      }
      const int i4 = uu & 1, i5 = (uu + 1) & 1;
#pragma unroll
      for (int t = 0; t < 2; t++) {
        f4 z4 = {0.f, 0.f, 0.f, 0.f};
        f4 s1a = z4, s1b = z4, s2a = z4, s2b = z4, s3a = z4, s3b = z4;
        s1a = mf(WH[t][0], bh[0], s1a); s1b = mf(WH[t][1], bh[1], s1b);
        s2a = mf(WH[t][0], bl[0], s2a); s2b = mf(WH[t][1], bl[1], s2b);
        s3a = mf(WL[t][0], bh[0], s3a); s3b = mf(WL[t][1], bh[1], s3b);
        s1a = mf(WH[t][2], bh[2], s1a); s1b = mf(WH[t][3], bh[3], s1b);
        s2a = mf(WH[t][2], bl[2], s2a); s2b = mf(WH[t][3], bl[3], s2b);
        s3a = mf(WL[t][2], bh[2], s3a); s3b = mf(WL[t][3], bh[3], s3b);
        s1a = mf(WH[t][4], uh[i4], s1a); s1b = mf(WH[t][5], uh[i5], s1b);
        s2a = mf(WH[t][4], ul[i4], s2a); s2b = mf(WH[t][5], ul[i5], s2b);
        s3a = mf(WL[t][4], uh[i4], s3a); s3b = mf(WL[t][5], uh[i5], s3b);
        float wv[4];
#pragma unroll
        for (int r = 0; r < 4; r++)
          wv[r] = ftanh(((s1a[r] + s1b[r]) + (s2a[r] + s2b[r])) + (s3a[r] + s3b[r]));
        int h0, l0, h1, l1;
        split2(wv[0], wv[1], h0, l0);
        split2(wv[2], wv[3], h1, l1);
        const int zt = Z0 + t;
        const int widx = (2 * (zt & 1) + (q >> 1)) * 68 + nn * 4 + 2 * (q & 1);
        i2 wh; wh[0] = h0; wh[1] = h1;
        i2 wl; wl[0] = l0; wl[1] = l1;
        *(i2*)&lds[rb ^ 1][4 + (zt >> 1)][widx] = wh;
        *(i2*)&lds[rb ^ 1][6 + (zt >> 1)][widx] = wl;
      }
      f4 a = ra0[(uu + 2) & 3], b = ra1[(uu + 2) & 3];
      float t8[8] = {a[0], a[1], a[2], a[3], b[0], b[1], b[2], b[3]};
      split8(t8, uh[uu & 1], ul[uu & 1]);
      const int kp = (kk + 6 < NT) ? kk + 6 : NT - 1;
      const f4* p = (const f4*)(pu + (size_t)kp * 32);
      ra0[(uu + 2) & 3] = p[0];
      ra1[(uu + 2) & 3] = p[1];
      lds_barrier();
    };
    for (int k = 0; k < NT; k += 4) {
      zstep(k, 0); zstep(k + 1, 1); zstep(k + 2, 2); zstep(k + 3, 3);
    }
  } else {
    const int X0 = (wave - 2) * 2;
    Frag WXH[2][5], WXL[2][5], WYH[2][5];
#pragma unroll
    for (int t = 0; t < 2; t++)
#pragma unroll
      for (int c = 0; c < 5; c++) {
        wfrag(Wfull, 16 * (X0 + t), c, lane, WXH[t][c], WXL[t][c]);
        Frag dmy;
        wfrag(Wfull, 128 + 16 * (X0 + t), c, lane, WYH[t][c], dmy);
      }
    float* py0 = out + (size_t)(b0 + nn) * (NT * 64) + 16 * X0 + 4 * q;
    auto xstep = [&](int kk, int uu) {
      const int rb = uu & 1;
      Frag bh[4], bl[4];
#pragma unroll
      for (int c = 0; c < 4; c++) {
        const int s = (c < 2) ? c : 2 + c;
        bh[c].v = *(const short8*)&lds[rb][s][ro];
        bl[c].v = *(const short8*)&lds[rb][s + 2][ro];
      }
      const int i4 = uu & 1;
#pragma unroll
      for (int t = 0; t < 2; t++) {
        f4 z4 = {0.f, 0.f, 0.f, 0.f};
        f4 s1 = z4, s2 = z4, s3 = z4, sy = z4;
#pragma unroll
        for (int c = 0; c < 4; c++) {
          s1 = mf(WXH[t][c], bh[c], s1);
          s2 = mf(WXH[t][c], bl[c], s2);
          s3 = mf(WXL[t][c], bh[c], s3);
          sy = mf(WYH[t][c], bh[c], sy);
        }
        s1 = mf(WXH[t][4], uh[i4], s1);
        s2 = mf(WXH[t][4], ul[i4], s2);
        s3 = mf(WXL[t][4], uh[i4], s3);
        sy = mf(WYH[t][4], uh[i4], sy);
        float xv[4];
#pragma unroll
        for (int r = 0; r < 4; r++) xv[r] = s1[r] + s2[r] + s3[r];
        int h0, l0, h1, l1;
        split2(xv[0], xv[1], h0, l0);
        split2(xv[2], xv[3], h1, l1);
        const int xt = X0 + t;
        const int widx = (2 * (xt & 1) + (q >> 1)) * 68 + nn * 4 + 2 * (q & 1);
        i2 wh; wh[0] = h0; wh[1] = h1;
        i2 wl; wl[0] = l0; wl[1] = l1;
        *(i2*)&lds[rb ^ 1][(xt >> 1)][widx] = wh;
        *(i2*)&lds[rb ^ 1][2 + (xt >> 1)][widx] = wl;
        *(f4*)(py0 + (size_t)kk * 64 + 16 * t) = sy;
      }
      f4 a = ra0[(uu + 2) & 3], b = ra1[(uu + 2) & 3];
      float t8[8] = {a[0], a[1], a[2], a[3], b[0], b[1], b[2], b[3]};
      split8(t8, uh[uu & 1], ul[uu & 1]);
      const int kp = (kk + 6 < NT) ? kk + 6 : NT - 1;
      const f4* p = (const f4*)(pu + (size_t)kp * 32);
      ra0[(uu + 2) & 3] = p[0];
      ra1[(uu + 2) & 3] = p[1];
      lds_barrier();
    };
    for (int k = 0; k < NT; k += 4) {
      xstep(k, 0); xstep(k + 1, 1); xstep(k + 2, 2); xstep(k + 3, 3);
    }
  }
}

extern "C" void kernel_launch(void* const* d_in, const int* in_sizes, int n_in,
                              void* d_out, int out_size, void* d_ws, size_t ws_size,
                              hipStream_t stream) {
  const float* x0  = (const float*)d_in[0];
  const float* us  = (const float*)d_in[1];
  const float* A   = (const float*)d_in[2];
  const float* B1  = (const float*)d_in[3];
  const float* B2  = (const float*)d_in[4];
  const float* C1  = (const float*)d_in[5];
  const float* D11 = (const float*)d_in[6];
  const float* D12 = (const float*)d_in[7];
  const float* C2  = (const float*)d_in[8];
  const float* D21 = (const float*)d_in[9];
  float* Wfull = (float*)d_ws;  // 147456 bytes
  const size_t W_BYTES = (size_t)192 * 192 * 4;
  float* UU = (float*)((char*)d_ws + W_BYTES);
  const size_t UU_BYTES = (size_t)NT * 8 * 12 * 256 * 4;  // 201.3 MB
  const bool pre = ws_size >= W_BYTES + UU_BYTES;
  float* out = (float*)d_out;

  prep_w<<<dim3(192), dim3(192), 0, stream>>>(A, B1, B2, C1, D11, D12, C2, D21, Wfull);
  if (pre) {
    prep_uu<<<dim3(8, 64), dim3(256), 0, stream>>>(us, Wfull, UU);
    lure_seqp<<<dim3(16), dim3(512), 0, stream>>>(x0, us, C2, D21, Wfull, UU, out);
  } else {
    lure_seq_fb<<<dim3(8), dim3(256), 0, stream>>>(x0, us, C2, D21, Wfull, out);
  }
}

// Round 6
// 983.709 us; speedup vs baseline: 1.5470x; 1.0217x over previous
//
#include <hip/hip_runtime.h>

// Lure RNN, latency-bound sequential chain.
// R9: R8 structure (16 blocks x 8 batches, hi|lo column packing, fused s1|s2
// MFMA) + critical-chain cuts: (1) 2-way split MFMA accumulator chains
// (4-deep -> 2-deep + add) for all tanh/split-feeding sums; (2) in-loop
// bf16 split via v_cvt_pk_bf16_f32 (1 op packs 2 RNE bf16; was ~14-op magic
// RNE); (3) peeled final k-group so main-loop prefetch is unconditional.
// R8 post-mortem: no pipe saturated (LDS 510 / VALU 565 / MFMA 390 of a
// 1008-cyc step) -> serial-dependency bound; these cuts shorten the chain.
// prep_w/prep_uu = R5-exact (verified).

#define NT 2048

typedef __attribute__((ext_vector_type(8))) short short8;
typedef __attribute__((ext_vector_type(4))) float f4;
typedef __attribute__((ext_vector_type(2))) int i2;

union Frag { int i[4]; i2 h[2]; short8 v; };

__device__ __forceinline__ unsigned rne_bf16(float f) {
  unsigned u = __float_as_uint(f);
  return (u + 0x7FFFu + ((u >> 16) & 1u)) >> 16;
}
__device__ __forceinline__ void split2(float a, float b, int& hi, int& lo) {
  unsigned ha = rne_bf16(a), hb = rne_bf16(b);
  float ra = a - __uint_as_float(ha << 16);
  float rb = b - __uint_as_float(hb << 16);
  hi = (int)(ha | (hb << 16));
  lo = (int)(rne_bf16(ra) | (rne_bf16(rb) << 16));
}
__device__ __forceinline__ void split8(const float* x, Frag& hi, Frag& lo) {
#pragma unroll
  for (int p = 0; p < 4; p++) split2(x[2 * p], x[2 * p + 1], hi.i[p], lo.i[p]);
}
// One-instruction RNE pack of 2 f32 -> 2 bf16 (low16 = a, high16 = b).
__device__ __forceinline__ int cvtpk(float a, float b) {
  int r;
  asm("v_cvt_pk_bf16_f32 %0, %1, %2" : "=v"(r) : "v"(a), "v"(b));
  return r;
}
// cvt_pk-based split2: same RNE rounding as split2, ~6 ops instead of ~14.
__device__ __forceinline__ void split2c(float a, float b, int& hi, int& lo) {
  hi = cvtpk(a, b);
  float ra = a - __uint_as_float((unsigned)hi << 16);
  float rb = b - __uint_as_float((unsigned)hi & 0xFFFF0000u);
  lo = cvtpk(ra, rb);
}
__device__ __forceinline__ float ftanh(float x) {
  float e = __expf(2.0f * x);
  return 1.0f - 2.0f * __builtin_amdgcn_rcpf(e + 1.0f);
}
__device__ __forceinline__ f4 mf(const Frag& a, const Frag& b, f4 c) {
  return __builtin_amdgcn_mfma_f32_16x16x32_bf16(a.v, b.v, c, 0, 0, 0);
}
// lane <- lane^8 within each 16-lane row (VALU DPP, no LDS pipe)
__device__ __forceinline__ float ror8f(float x) {
  return __int_as_float(
      __builtin_amdgcn_mov_dpp(__float_as_int(x), 0x128, 0xf, 0xf, true));
}
// Barrier with LDS-only drain: keeps global loads (vmcnt) in flight across steps.
__device__ __forceinline__ void lds_barrier() {
  __builtin_amdgcn_s_waitcnt(0xC07F);  // lgkmcnt(0), vmcnt=63, expcnt=7
  __builtin_amdgcn_s_barrier();
}
__device__ __forceinline__ void wfrag(const float* W, int row0, int c, int lane,
                                      Frag& hi, Frag& lo) {
  const int m = lane & 15, qq = lane >> 4;
  const f4* p = (const f4*)(W + (size_t)(row0 + m) * 192 + 32 * c + 8 * qq);
  f4 a = p[0], b = p[1];
  float t[8] = {a[0], a[1], a[2], a[3], b[0], b[1], b[2], b[3]};
  split8(t, hi, lo);
}

// ---- prep_w: build Wfull [192 x 192] fp32 ----
// rows 0..63 (x'): [A | B2 | B1 | 0]; 64..127 (z~'): [C2A | C2B2 | C2B1 | D21];
// 128..191 (y): [C1A | C1B2+D12 | C1B1+D11 | 0]
__global__ void prep_w(const float* __restrict__ A, const float* __restrict__ B1,
                       const float* __restrict__ B2, const float* __restrict__ C1,
                       const float* __restrict__ D11, const float* __restrict__ D12,
                       const float* __restrict__ C2, const float* __restrict__ D21,
                       float* __restrict__ Wfull) {
  const int r = blockIdx.x;   // 0..191
  const int c = threadIdx.x;  // 0..191
  float v = 0.f;
  if (c < 64) {
    const int j = c;
    if (r < 64) v = A[r * 64 + j];
    else if (r < 128) { float s = 0.f; for (int l = 0; l < 64; l++) s += C2[(r - 64) * 64 + l] * A[l * 64 + j]; v = s; }
    else { float s = 0.f; for (int l = 0; l < 64; l++) s += C1[(r - 128) * 64 + l] * A[l * 64 + j]; v = s; }
  } else if (c < 128) {
    const int j = c - 64;
    if (r < 64) v = B2[r * 64 + j];
    else if (r < 128) { float s = 0.f; for (int l = 0; l < 64; l++) s += C2[(r - 64) * 64 + l] * B2[l * 64 + j]; v = s; }
    else { float s = 0.f; for (int l = 0; l < 64; l++) s += C1[(r - 128) * 64 + l] * B2[l * 64 + j]; v = s + D12[(r - 128) * 64 + j]; }
  } else if (c < 160) {
    const int j = c - 128;
    if (r < 64) v = B1[r * 32 + j];
    else if (r < 128) { float s = 0.f; for (int l = 0; l < 64; l++) s += C2[(r - 64) * 64 + l] * B1[l * 32 + j]; v = s; }
    else { float s = 0.f; for (int l = 0; l < 64; l++) s += C1[(r - 128) * 64 + l] * B1[l * 32 + j]; v = s + D11[(r - 128) * 32 + j]; }
  } else {
    const int j = c - 160;
    v = (r >= 64 && r < 128) ? D21[(r - 64) * 32 + j] : 0.f;
  }
  Wfull[r * 192 + c] = v;
}

// ---- prep_uu: MFMA-based u-projection (R5, verified) ----
// UU[k][blk:8][tt:12][lane:64][4] in D-fragment order of mfma_f32_16x16x32:
//   tt 0..3: z rows 64+16t  (C2B1 u_k + D21 u_{k+1}; W cols 128..191, K=64)
//   tt 4..7: x rows 16t     (B1 u_k;                 W cols 128..159, K=32)
//   tt 8..11: y rows 128+16t ((C1B1+D11) u_k;        W cols 128..159, K=32)
__global__ __launch_bounds__(256)
void prep_uu(const float* __restrict__ us, const float* __restrict__ Wfull,
             float* __restrict__ UU) {
  const int blk = blockIdx.x;        // 0..7 (batch group of 16)
  const int kc = blockIdx.y;         // 0..63 (32 k each)
  const int wv = threadIdx.x >> 6;   // 0..3 (tile row-group)
  const int lane = threadIdx.x & 63;
  const int nn = lane & 15, q = lane >> 4;
  const int b0 = blk * 16;

  Frag zh4, zl4, zh5, zl5, xh4, xl4, yh4, yl4;
  wfrag(Wfull, 64 + 16 * wv, 4, lane, zh4, zl4);
  wfrag(Wfull, 64 + 16 * wv, 5, lane, zh5, zl5);
  wfrag(Wfull, 16 * wv, 4, lane, xh4, xl4);
  wfrag(Wfull, 128 + 16 * wv, 4, lane, yh4, yl4);

  const float* ubase = us + (size_t)(b0 + nn) * (NT * 32) + 8 * q;

  int k = kc * 32;
  Frag uhc, ulc, uhn, uln;
  {  // cur = u_k
    const f4* p = (const f4*)(ubase + (size_t)k * 32);
    f4 a = p[0], b = p[1];
    float t[8] = {a[0], a[1], a[2], a[3], b[0], b[1], b[2], b[3]};
    split8(t, uhc, ulc);
  }
  f4 ra, rb;
  {  // raw next = u_{k+1}
    const int kn = (k + 1 < NT) ? k + 1 : NT - 1;
    const f4* p = (const f4*)(ubase + (size_t)kn * 32);
    ra = p[0]; rb = p[1];
  }
  for (int k0 = 0; k0 < 32; k0++, k++) {
    {
      float t[8] = {ra[0], ra[1], ra[2], ra[3], rb[0], rb[1], rb[2], rb[3]};
      split8(t, uhn, uln);
    }
    {  // prefetch raw u_{k+2}
      const int kp = (k + 2 < NT) ? k + 2 : NT - 1;
      const f4* p = (const f4*)(ubase + (size_t)kp * 32);
      ra = p[0]; rb = p[1];
    }
    f4 az = {0.f, 0.f, 0.f, 0.f}, ax = az, ay = az;
    az = mf(zh4, uhc, az); az = mf(zh5, uhn, az);
    az = mf(zh4, ulc, az); az = mf(zh5, uln, az);
    az = mf(zl4, uhc, az); az = mf(zl5, uhn, az);
    ax = mf(xh4, uhc, ax); ax = mf(xh4, ulc, ax); ax = mf(xl4, uhc, ax);
    ay = mf(yh4, uhc, ay); ay = mf(yh4, ulc, ay); ay = mf(yl4, uhc, ay);
    float* dst = UU + ((size_t)k * 8 + blk) * 3072 + lane * 4;
    *(f4*)(dst + wv * 256) = az;
    *(f4*)(dst + (4 + wv) * 256) = ax;
    *(f4*)(dst + (8 + wv) * 256) = ay;
    uhc = uhn; ulc = uln;
  }
}

// ---- sequential recurrence (R9): 16 blocks x 512 threads, 8 batches each ----
// LDS regions per buffer: 0,1 = x chunks (K 0-31, 32-63); 2,3 = w chunks.
// Region layout: [4 k-groups x 68 dw]; within a group, dw nn*4: nn<8 = hi of
// batch nn, nn>=8 = lo of batch nn-8. One b128 read feeds hi (MFMA cols 0-7)
// and lo (cols 8-15) simultaneously; s2 reaches cols 0-7 via ror8f DPP.
__global__ __launch_bounds__(512, 1)
void lure_seqp(const float* __restrict__ x0, const float* __restrict__ us,
               const float* __restrict__ C2, const float* __restrict__ D21,
               const float* __restrict__ Wfull, const float* __restrict__ UU,
               float* __restrict__ out) {
  __shared__ int lds[2][4][272];
  const int tid = threadIdx.x;
  const int wave = tid >> 6;
  const int lane = tid & 63;
  const int q = lane >> 4;
  const int nn = lane & 15;
  const int b8 = blockIdx.x * 8;
  const int ro = q * 68 + nn * 4;
  const size_t KSTRIDE = 8 * 12 * 256;  // floats per k in UU
  const int ob = blockIdx.x >> 1, hh = blockIdx.x & 1;
  const int ulane = 8 * hh + (lane & 7) + 16 * q;  // UU lane remap (8-batch)
  const float msk = (lane & 8) ? 0.f : 1.f;        // valid-column mask

  // ---- prologue (threads 0..127): x_0 and w_0 packed into buffer 0 ----
  if (tid < 128) {
    const int n = tid >> 4;          // batch 0..7
    const int f0 = (tid & 15) * 4;   // rows f0..f0+3
    const int c = f0 >> 5;           // chunk
    const int g = (f0 & 31) >> 3;    // k-group
    const int d = (f0 & 7) >> 1;     // dw offset
    const int idx = g * 68 + n * 4 + d;
    const float* xrow = x0 + (b8 + n) * 64;
    float xv[4] = {xrow[f0], xrow[f0 + 1], xrow[f0 + 2], xrow[f0 + 3]};
    int h0, l0, h1, l1;
    split2(xv[0], xv[1], h0, l0);
    split2(xv[2], xv[3], h1, l1);
    lds[0][c][idx] = h0;       lds[0][c][idx + 1] = h1;
    lds[0][c][idx + 32] = l0;  lds[0][c][idx + 33] = l1;
    float zv[4] = {0.f, 0.f, 0.f, 0.f};
    for (int j = 0; j < 64; j++) {
      float xj = xrow[j];
#pragma unroll
      for (int r = 0; r < 4; r++) zv[r] += C2[(f0 + r) * 64 + j] * xj;
    }
    const float* urow = us + (size_t)(b8 + n) * (NT * 32);
    for (int j = 0; j < 32; j++) {
      float uj = urow[j];
#pragma unroll
      for (int r = 0; r < 4; r++) zv[r] += D21[(f0 + r) * 32 + j] * uj;
    }
#pragma unroll
    for (int r = 0; r < 4; r++) zv[r] = ftanh(zv[r]);
    split2(zv[0], zv[1], h0, l0);
    split2(zv[2], zv[3], h1, l1);
    lds[0][2 + c][idx] = h0;       lds[0][2 + c][idx + 1] = h1;
    lds[0][2 + c][idx + 32] = l0;  lds[0][2 + c][idx + 33] = l1;
  }

  if (wave < 4) {
    // ---- z-wave: rows 64+16*zt. Fused s1|s2 (A=WH) + s3 (A=WL), 2-way split chains. ----
    const int zt = wave;
    Frag WH[4], WL[4];
#pragma unroll
    for (int c = 0; c < 4; c++) wfrag(Wfull, 64 + 16 * zt, c, lane, WH[c], WL[c]);
    const float* up = UU + (((size_t)ob * 12 + zt) * 64 + ulane) * 4;
    f4 uz[4];
#pragma unroll
    for (int d = 0; d < 4; d++) uz[d] = *(const f4*)(up + (size_t)d * KSTRIDE);
    const int widx = (2 * (zt & 1) + (q >> 1)) * 68 + nn * 4 + 2 * (q & 1);
    const int rw = 2 + (zt >> 1);
    lds_barrier();

    auto zstep = [&](int kk, int d, int kp) {
      const int rb = kk & 1;
      Frag b[4];
#pragma unroll
      for (int c = 0; c < 4; c++) b[c].v = *(const short8*)&lds[rb][c][ro];
      f4 sA0 = {uz[d][0] * msk, uz[d][1] * msk, uz[d][2] * msk, uz[d][3] * msk};
      f4 z4 = {0.f, 0.f, 0.f, 0.f};
      f4 sA1 = z4, sB0 = z4, sB1 = z4;
      sA0 = mf(WH[0], b[0], sA0); sB0 = mf(WL[0], b[0], sB0);
      sA1 = mf(WH[1], b[1], sA1); sB1 = mf(WL[1], b[1], sB1);
      sA0 = mf(WH[2], b[2], sA0); sB0 = mf(WL[2], b[2], sB0);
      sA1 = mf(WH[3], b[3], sA1); sB1 = mf(WL[3], b[3], sB1);
      uz[d] = *(const f4*)(up + (size_t)kp * KSTRIDE);
      float wv[4];
#pragma unroll
      for (int r = 0; r < 4; r++) {
        float aa = sA0[r] + sA1[r];
        wv[r] = ftanh(aa + ror8f(aa) + (sB0[r] + sB1[r]));
      }
      int h0, l0, h1, l1;
      split2c(wv[0], wv[1], h0, l0);
      split2c(wv[2], wv[3], h1, l1);
      if ((lane & 8) == 0) {
        i2 wh; wh[0] = h0; wh[1] = h1;
        i2 wl; wl[0] = l0; wl[1] = l1;
        *(i2*)&lds[rb ^ 1][rw][widx] = wh;
        *(i2*)&lds[rb ^ 1][rw][widx + 32] = wl;
      }
      lds_barrier();
    };
    int k = 0;
    for (; k < NT - 4; k += 4) {
      zstep(k, 0, k + 4); zstep(k + 1, 1, k + 5);
      zstep(k + 2, 2, k + 6); zstep(k + 3, 3, k + 7);
    }
    zstep(k, 0, NT - 1); zstep(k + 1, 1, NT - 1);
    zstep(k + 2, 2, NT - 1); zstep(k + 3, 3, NT - 1);
  } else {
    // ---- x-wave: x'-tile (fused t1|t2 + t3, split chains) + y-tile (1-term) ----
    const int xt = wave - 4;
    Frag WXH[4], WXL[4], WYH[4];
#pragma unroll
    for (int c = 0; c < 4; c++) {
      wfrag(Wfull, 16 * xt, c, lane, WXH[c], WXL[c]);
      Frag dmy;
      wfrag(Wfull, 128 + 16 * xt, c, lane, WYH[c], dmy);
    }
    const float* upx = UU + (((size_t)ob * 12 + 4 + xt) * 64 + ulane) * 4;
    const float* upy = UU + (((size_t)ob * 12 + 8 + xt) * 64 + ulane) * 4;
    f4 ux[4], uy[4];
#pragma unroll
    for (int d = 0; d < 4; d++) {
      ux[d] = *(const f4*)(upx + (size_t)d * KSTRIDE);
      uy[d] = *(const f4*)(upy + (size_t)d * KSTRIDE);
    }
    const int widx = (2 * (xt & 1) + (q >> 1)) * 68 + nn * 4 + 2 * (q & 1);
    const int rw = (xt >> 1);
    float* py0 = out + (size_t)(b8 + nn) * (NT * 64) + 16 * xt + 4 * q;
    lds_barrier();

    auto xstep = [&](int kk, int d, int kp) {
      const int rb = kk & 1;
      Frag b[4];
#pragma unroll
      for (int c = 0; c < 4; c++) b[c].v = *(const short8*)&lds[rb][c][ro];
      f4 tA0 = {ux[d][0] * msk, ux[d][1] * msk, ux[d][2] * msk, ux[d][3] * msk};
      f4 z4 = {0.f, 0.f, 0.f, 0.f};
      f4 tA1 = z4, tB0 = z4, tB1 = z4;
      f4 sy = uy[d];
      tA0 = mf(WXH[0], b[0], tA0); tB0 = mf(WXL[0], b[0], tB0);
      tA1 = mf(WXH[1], b[1], tA1); tB1 = mf(WXL[1], b[1], tB1);
      sy = mf(WYH[0], b[0], sy);   sy = mf(WYH[1], b[1], sy);
      tA0 = mf(WXH[2], b[2], tA0); tB0 = mf(WXL[2], b[2], tB0);
      tA1 = mf(WXH[3], b[3], tA1); tB1 = mf(WXL[3], b[3], tB1);
      sy = mf(WYH[2], b[2], sy);   sy = mf(WYH[3], b[3], sy);
      ux[d] = *(const f4*)(upx + (size_t)kp * KSTRIDE);
      uy[d] = *(const f4*)(upy + (size_t)kp * KSTRIDE);
      float xv[4];
#pragma unroll
      for (int r = 0; r < 4; r++) {
        float aa = tA0[r] + tA1[r];
        xv[r] = aa + ror8f(aa) + (tB0[r] + tB1[r]);
      }
      int h0, l0, h1, l1;
      split2c(xv[0], xv[1], h0, l0);
      split2c(xv[2], xv[3], h1, l1);
      if ((lane & 8) == 0) {
        i2 wh; wh[0] = h0; wh[1] = h1;
        i2 wl; wl[0] = l0; wl[1] = l1;
        *(i2*)&lds[rb ^ 1][rw][widx] = wh;
        *(i2*)&lds[rb ^ 1][rw][widx + 32] = wl;
        *(f4*)(py0 + (size_t)kk * 64) = sy;
      }
      lds_barrier();
    };
    int k = 0;
    for (; k < NT - 4; k += 4) {
      xstep(k, 0, k + 4); xstep(k + 1, 1, k + 5);
      xstep(k + 2, 2, k + 6); xstep(k + 3, 3, k + 7);
    }
    xstep(k, 0, NT - 1); xstep(k + 1, 1, NT - 1);
    xstep(k + 2, 2, NT - 1); xstep(k + 3, 3, NT - 1);
  }
}

// ---- fallback (ws too small for UU): R3's 4-wave kernel, Wfull only ----
__global__ __launch_bounds__(256, 1)
void lure_seq_fb(const float* __restrict__ x0, const float* __restrict__ us,
                 const float* __restrict__ C2, const float* __restrict__ D21,
                 const float* __restrict__ Wfull, float* __restrict__ out) {
  __shared__ int lds[2][8][272];
  const int tid = threadIdx.x;
  const int wave = tid >> 6;
  const int lane = tid & 63;
  const int q = lane >> 4;
  const int nn = lane & 15;
  const int b0 = blockIdx.x * 16;
  const int ro = q * 68 + nn * 4;
  {
    const int n = tid >> 4;
    const int f0 = (tid & 15) * 4;
    const int cc = f0 >> 5;
    const int g = (f0 & 31) >> 3;
    const int d = (f0 & 7) >> 1;
    const int idx = g * 68 + n * 4 + d;
    const float* xrow = x0 + (b0 + n) * 64;
    float xv[4] = {xrow[f0], xrow[f0 + 1], xrow[f0 + 2], xrow[f0 + 3]};
    int h0, l0, h1, l1;
    split2(xv[0], xv[1], h0, l0);
    split2(xv[2], xv[3], h1, l1);
    lds[0][cc][idx] = h0;     lds[0][cc][idx + 1] = h1;
    lds[0][2 + cc][idx] = l0; lds[0][2 + cc][idx + 1] = l1;
    float zv[4] = {0.f, 0.f, 0.f, 0.f};
    for (int j = 0; j < 64; j++) {
      float xj = xrow[j];
#pragma unroll
      for (int r = 0; r < 4; r++) zv[r] += C2[(f0 + r) * 64 + j] * xj;
    }
    const float* urow = us + (size_t)(b0 + n) * (NT * 32);
    for (int j = 0; j < 32; j++) {
      float uj = urow[j];
#pragma unroll
      for (int r = 0; r < 4; r++) zv[r] += D21[(f0 + r) * 32 + j] * uj;
    }
#pragma unroll
    for (int r = 0; r < 4; r++) zv[r] = ftanh(zv[r]);
    split2(zv[0], zv[1], h0, l0);
    split2(zv[2], zv[3], h1, l1);
    lds[0][4 + cc][idx] = h0; lds[0][4 + cc][idx + 1] = h1;
    lds[0][6 + cc][idx] = l0; lds[0][6 + cc][idx + 1] = l1;
  }
  Frag uh[2], ul[2];
  f4 ra0[4], ra1[4];
  const float* pu = us + ((size_t)(b0 + nn) * NT) * 32 + 8 * q;
#pragma unroll
  for (int j = 0; j < 2; j++) {
    const f4* p = (const f4*)(pu + j * 32);
    f4 a = p[0], b = p[1];
    float t[8] = {a[0], a[1], a[2], a[3], b[0], b[1], b[2], b[3]};
    split8(t, uh[j], ul[j]);
  }
#pragma unroll
  for (int j = 2; j <= 5; j++) {
    const f4* p = (const f4*)(pu + j * 32);
    ra0[j & 3] = p[0];
    ra1[j & 3] = p[1];
  }
  lds_barrier();

  if (wave < 2) {
    const int Z0 = wave * 2;
    Frag WH[2][6], WL[2][6];
#pragma unroll
    for (int t = 0; t < 2; t++)
#pragma unroll
      for (int c = 0; c < 6; c++)
        wfrag(Wfull, 64 + 16 * (Z0 + t), c, lane, WH[t][c], WL[t][c]);
    auto zstep = [&](int kk, int uu) {
      const int rb = uu & 1;
      Frag bh[4], bl[4];
#pragma unroll
      for (int c = 0; c < 4; c++) {
        const int s = (c < 2) ? c : 2 + c;
        bh[c].v = *(const short8*)&lds[rb][s][ro];
        bl[c].v = *(const short8*)&lds[rb][s + 2][ro];
      }
      const int i4 = uu & 1, i5 = (uu + 1) & 1;
#pragma unroll
      for (int t = 0; t < 2; t++) {
        f4 z4 = {0.f, 0.f, 0.f, 0.f};
        f4 s1a = z4, s1b = z4, s2a = z4, s2b = z4, s3a = z4, s3b = z4;
        s1a = mf(WH[t][0], bh[0], s1a); s1b = mf(WH[t][1], bh[1], s1b);
        s2a = mf(WH[t][0], bl[0], s2a); s2b = mf(WH[t][1], bl[1], s2b);
        s3a = mf(WL[t][0], bh[0], s3a); s3b = mf(WL[t][1], bh[1], s3b);
        s1a = mf(WH[t][2], bh[2], s1a); s1b = mf(WH[t][3], bh[3], s1b);
        s2a = mf(WH[t][2], bl[2], s2a); s2b = mf(WH[t][3], bl[3], s2b);
        s3a = mf(WL[t][2], bh[2], s3a); s3b = mf(WL[t][3], bh[3], s3b);
        s1a = mf(WH[t][4], uh[i4], s1a); s1b = mf(WH[t][5], uh[i5], s1b);
        s2a = mf(WH[t][4], ul[i4], s2a); s2b = mf(WH[t][5], ul[i5], s2b);
        s3a = mf(WL[t][4], uh[i4], s3a); s3b = mf(WL[t][5], uh[i5], s3b);
        float wv[4];
#pragma unroll
        for (int r = 0; r < 4; r++)
          wv[r] = ftanh(((s1a[r] + s1b[r]) + (s2a[r] + s2b[r])) + (s3a[r] + s3b[r]));
        int h0, l0, h1, l1;
        split2(wv[0], wv[1], h0, l0);
        split2(wv[2], wv[3], h1, l1);
        const int zt = Z0 + t;
        const int widx = (2 * (zt & 1) + (q >> 1)) * 68 + nn * 4 + 2 * (q & 1);
        i2 wh; wh[0] = h0; wh[1] = h1;
        i2 wl; wl[0] = l0; wl[1] = l1;
        *(i2*)&lds[rb ^ 1][4 + (zt >> 1)][widx] = wh;
        *(i2*)&lds[rb ^ 1][6 + (zt >> 1)][widx] = wl;
      }
      f4 a = ra0[(uu + 2) & 3], b = ra1[(uu + 2) & 3];
      float t8[8] = {a[0], a[1], a[2], a[3], b[0], b[1], b[2], b[3]};
      split8(t8, uh[uu & 1], ul[uu & 1]);
      const int kp = (kk + 6 < NT) ? kk + 6 : NT - 1;
      const f4* p = (const f4*)(pu + (size_t)kp * 32);
      ra0[(uu + 2) & 3] = p[0];
      ra1[(uu + 2) & 3] = p[1];
      lds_barrier();
    };
    for (int k = 0; k < NT; k += 4) {
      zstep(k, 0); zstep(k + 1, 1); zstep(k + 2, 2); zstep(k + 3, 3);
    }
  } else {
    const int X0 = (wave - 2) * 2;
    Frag WXH[2][5], WXL[2][5], WYH[2][5];
#pragma unroll
    for (int t = 0; t < 2; t++)
#pragma unroll
      for (int c = 0; c < 5; c++) {
        wfrag(Wfull, 16 * (X0 + t), c, lane, WXH[t][c], WXL[t][c]);
        Frag dmy;
        wfrag(Wfull, 128 + 16 * (X0 + t), c, lane, WYH[t][c], dmy);
      }
    float* py0 = out + (size_t)(b0 + nn) * (NT * 64) + 16 * X0 + 4 * q;
    auto xstep = [&](int kk, int uu) {
      const int rb = uu & 1;
      Frag bh[4], bl[4];
#pragma unroll
      for (int c = 0; c < 4; c++) {
        const int s = (c < 2) ? c : 2 + c;
        bh[c].v = *(const short8*)&lds[rb][s][ro];
        bl[c].v = *(const short8*)&lds[rb][s + 2][ro];
      }
      const int i4 = uu & 1;
#pragma unroll
      for (int t = 0; t < 2; t++) {
        f4 z4 = {0.f, 0.f, 0.f, 0.f};
        f4 s1 = z4, s2 = z4, s3 = z4, sy = z4;
#pragma unroll
        for (int c = 0; c < 4; c++) {
          s1 = mf(WXH[t][c], bh[c], s1);
          s2 = mf(WXH[t][c], bl[c], s2);
          s3 = mf(WXL[t][c], bh[c], s3);
          sy = mf(WYH[t][c], bh[c], sy);
        }
        s1 = mf(WXH[t][4], uh[i4], s1);
        s2 = mf(WXH[t][4], ul[i4], s2);
        s3 = mf(WXL[t][4], uh[i4], s3);
        sy = mf(WYH[t][4], uh[i4], sy);
        float xv[4];
#pragma unroll
        for (int r = 0; r < 4; r++) xv[r] = s1[r] + s2[r] + s3[r];
        int h0, l0, h1, l1;
        split2(xv[0], xv[1], h0, l0);
        split2(xv[2], xv[3], h1, l1);
        const int xt = X0 + t;
        const int widx = (2 * (xt & 1) + (q >> 1)) * 68 + nn * 4 + 2 * (q & 1);
        i2 wh; wh[0] = h0; wh[1] = h1;
        i2 wl; wl[0] = l0; wl[1] = l1;
        *(i2*)&lds[rb ^ 1][(xt >> 1)][widx] = wh;
        *(i2*)&lds[rb ^ 1][2 + (xt >> 1)][widx] = wl;
        *(f4*)(py0 + (size_t)kk * 64 + 16 * t) = sy;
      }
      f4 a = ra0[(uu + 2) & 3], b = ra1[(uu + 2) & 3];
      float t8[8] = {a[0], a[1], a[2], a[3], b[0], b[1], b[2], b[3]};
      split8(t8, uh[uu & 1], ul[uu & 1]);
      const int kp = (kk + 6 < NT) ? kk + 6 : NT - 1;
      const f4* p = (const f4*)(pu + (size_t)kp * 32);
      ra0[(uu + 2) & 3] = p[0];
      ra1[(uu + 2) & 3] = p[1];
      lds_barrier();
    };
    for (int k = 0; k < NT; k += 4) {
      xstep(k, 0); xstep(k + 1, 1); xstep(k + 2, 2); xstep(k + 3, 3);
    }
  }
}

extern "C" void kernel_launch(void* const* d_in, const int* in_sizes, int n_in,
                              void* d_out, int out_size, void* d_ws, size_t ws_size,
                              hipStream_t stream) {
  const float* x0  = (const float*)d_in[0];
  const float* us  = (const float*)d_in[1];
  const float* A   = (const float*)d_in[2];
  const float* B1  = (const float*)d_in[3];
  const float* B2  = (const float*)d_in[4];
  const float* C1  = (const float*)d_in[5];
  const float* D11 = (const float*)d_in[6];
  const float* D12 = (const float*)d_in[7];
  const float* C2  = (const float*)d_in[8];
  const float* D21 = (const float*)d_in[9];
  float* Wfull = (float*)d_ws;  // 147456 bytes
  const size_t W_BYTES = (size_t)192 * 192 * 4;
  float* UU = (float*)((char*)d_ws + W_BYTES);
  const size_t UU_BYTES = (size_t)NT * 8 * 12 * 256 * 4;  // 201.3 MB
  const bool pre = ws_size >= W_BYTES + UU_BYTES;
  float* out = (float*)d_out;

  prep_w<<<dim3(192), dim3(192), 0, stream>>>(A, B1, B2, C1, D11, D12, C2, D21, Wfull);
  if (pre) {
    prep_uu<<<dim3(8, 64), dim3(256), 0, stream>>>(us, Wfull, UU);
    lure_seqp<<<dim3(16), dim3(512), 0, stream>>>(x0, us, C2, D21, Wfull, UU, out);
  } else {
    lure_seq_fb<<<dim3(8), dim3(256), 0, stream>>>(x0, us, C2, D21, Wfull, out);
  }
}